// Round 4
// baseline (41.653 us; speedup 1.0000x reference)
//
#include <hip/hip_runtime.h>
#include <math.h>

#define KS     3
#define ALPHA  0.1f
#define M      56
#define N      56
#define L      18
#define KK     18
#define PIX    (M * N)        // 3136
#define VEC    (PIX / 4)      // 784
#define WAVES  4
#define NTHR   (WAVES * 64)   // 256
#define COVER  (L * KS)       // 54
// 784 float4 per plane = 12 full rounds of 64 lanes + 16 tail

typedef float vf4 __attribute__((ext_vector_type(4)));   // clang vector: ok for nontemporal builtins

__device__ __forceinline__ float rmax4(vf4 x) {
    return fmaxf(fmaxf(x.x, x.y), fmaxf(x.z, x.w));
}

__device__ __forceinline__ vf4 proc4(vf4 x, int v, float peak, size_t base,
                                     const int* __restrict__ rc,
                                     const int* sm) {
    const int p0 = v * 4;
    const int i  = v / 14;          // = (4v)/56 ; all 4 elems share the row
    const int j0 = p0 - i * N;
    const bool inrow = (i < COVER);
    const int  mrow  = (i / 3) * KK;

    vf4 o;
#pragma unroll
    for (int e = 0; e < 4; ++e) {
        const float a = x[e];
        const int   j = j0 + e;
        bool cond;
        if (a == peak) {
            cond = (rc[base + (size_t)(p0 + e)] != 0);   // peak: rc decides
        } else {
            cond = inrow && (j < COVER) && (sm[mrow + j / 3] != 0);
        }
        o[e] = cond ? a * ALPHA : a;
    }
    return o;
}

__global__ __launch_bounds__(NTHR) void div_block_kernel(
    const float* __restrict__ act,
    const int*   __restrict__ rc,
    const int*   __restrict__ pmask,
    float*       __restrict__ out,
    int planes) {

    const int tid = threadIdx.x;
    const int w   = tid >> 6;           // wave id in block
    const int l   = tid & 63;           // lane id
    const int plane = blockIdx.x * WAVES + w;
    if (plane >= planes) return;        // no barriers anywhere -> safe

    const size_t base = (size_t)plane * PIX;
    const vf4* a4 = (const vf4*)(act + base);
    vf4*       o4 = (vf4*)(out + base);

    // per-wave patch mask in LDS (within-wave RAW only; no __syncthreads needed)
    __shared__ int smask[WAVES][L * KK];
    int* sm = smask[w];
    for (int s = l; s < L * KK; s += 64)
        sm[s] = pmask[(size_t)plane * (L * KK) + s];

    // ---- load whole plane into this wave's registers (13 float4/lane) ----
    vf4 x0  = a4[l];
    vf4 x1  = a4[l + 1 * 64];
    vf4 x2  = a4[l + 2 * 64];
    vf4 x3  = a4[l + 3 * 64];
    vf4 x4  = a4[l + 4 * 64];
    vf4 x5  = a4[l + 5 * 64];
    vf4 x6  = a4[l + 6 * 64];
    vf4 x7  = a4[l + 7 * 64];
    vf4 x8  = a4[l + 8 * 64];
    vf4 x9  = a4[l + 9 * 64];
    vf4 x10 = a4[l + 10 * 64];
    vf4 x11 = a4[l + 11 * 64];
    const bool has12 = (l < (VEC - 12 * 64));   // lanes 0..15
    vf4 x12;
    if (has12) x12 = a4[l + 12 * 64];
    else       x12 = (vf4){-INFINITY, -INFINITY, -INFINITY, -INFINITY};

    // ---- tree max within lane, then 64-lane butterfly (no LDS, no barrier) --
    float m0 = fmaxf(rmax4(x0),  rmax4(x1));
    float m1 = fmaxf(rmax4(x2),  rmax4(x3));
    float m2 = fmaxf(rmax4(x4),  rmax4(x5));
    float m3 = fmaxf(rmax4(x6),  rmax4(x7));
    float m4 = fmaxf(rmax4(x8),  rmax4(x9));
    float m5 = fmaxf(rmax4(x10), rmax4(x11));
    float mx = fmaxf(fmaxf(fmaxf(m0, m1), fmaxf(m2, m3)),
                     fmaxf(fmaxf(m4, m5), rmax4(x12)));
#pragma unroll
    for (int off = 32; off > 0; off >>= 1)
        mx = fmaxf(mx, __shfl_xor(mx, off, 64));
    const float peak = mx;

    // ---- apply + nontemporal store (out is never re-read; keep act in L3) --
    __builtin_nontemporal_store(proc4(x0,  l,           peak, base, rc, sm), &o4[l]);
    __builtin_nontemporal_store(proc4(x1,  l + 1 * 64,  peak, base, rc, sm), &o4[l + 1 * 64]);
    __builtin_nontemporal_store(proc4(x2,  l + 2 * 64,  peak, base, rc, sm), &o4[l + 2 * 64]);
    __builtin_nontemporal_store(proc4(x3,  l + 3 * 64,  peak, base, rc, sm), &o4[l + 3 * 64]);
    __builtin_nontemporal_store(proc4(x4,  l + 4 * 64,  peak, base, rc, sm), &o4[l + 4 * 64]);
    __builtin_nontemporal_store(proc4(x5,  l + 5 * 64,  peak, base, rc, sm), &o4[l + 5 * 64]);
    __builtin_nontemporal_store(proc4(x6,  l + 6 * 64,  peak, base, rc, sm), &o4[l + 6 * 64]);
    __builtin_nontemporal_store(proc4(x7,  l + 7 * 64,  peak, base, rc, sm), &o4[l + 7 * 64]);
    __builtin_nontemporal_store(proc4(x8,  l + 8 * 64,  peak, base, rc, sm), &o4[l + 8 * 64]);
    __builtin_nontemporal_store(proc4(x9,  l + 9 * 64,  peak, base, rc, sm), &o4[l + 9 * 64]);
    __builtin_nontemporal_store(proc4(x10, l + 10 * 64, peak, base, rc, sm), &o4[l + 10 * 64]);
    __builtin_nontemporal_store(proc4(x11, l + 11 * 64, peak, base, rc, sm), &o4[l + 11 * 64]);
    if (has12)
        __builtin_nontemporal_store(proc4(x12, l + 12 * 64, peak, base, rc, sm), &o4[l + 12 * 64]);
}

extern "C" void kernel_launch(void* const* d_in, const int* in_sizes, int n_in,
                              void* d_out, int out_size, void* d_ws, size_t ws_size,
                              hipStream_t stream) {
    const float* act   = (const float*)d_in[0];
    const int*   rc    = (const int*)d_in[1];
    const int*   pmask = (const int*)d_in[2];
    float*       out   = (float*)d_out;

    const int planes = in_sizes[0] / PIX;               // 32*256 = 8192
    const int blocks = (planes + WAVES - 1) / WAVES;    // 2048
    div_block_kernel<<<blocks, NTHR, 0, stream>>>(act, rc, pmask, out, planes);
}

// Round 5
// 41.594 us; speedup vs baseline: 1.0014x; 1.0014x over previous
//
#include <hip/hip_runtime.h>
#include <math.h>

#define KS     3
#define ALPHA  0.1f
#define M      56
#define N      56
#define L      18
#define KK     18
#define PIX    (M * N)        // 3136
#define VEC    (PIX / 4)      // 784 float4 per plane
#define WAVES  4
#define NTHR   (WAVES * 64)   // 256
#define COVER  (L * KS)       // 54
#define CHUNKS 13             // 12 full rounds of 64 lanes + 16-lane tail

typedef float vf4 __attribute__((ext_vector_type(4)));

__device__ __forceinline__ float rmax4(vf4 x) {
    return fmaxf(fmaxf(x.x, x.y), fmaxf(x.z, x.w));
}

__global__ __launch_bounds__(NTHR) void div_block_kernel(
    const float* __restrict__ act,
    const int*   __restrict__ rc,
    const int*   __restrict__ pmask,
    float*       __restrict__ out,
    int planes) {

    const int tid = threadIdx.x;
    const int w   = tid >> 6;           // wave id in block
    const int l   = tid & 63;           // lane id
    const int plane = blockIdx.x * WAVES + w;
    if (plane >= planes) return;        // no barriers anywhere -> safe

    const size_t base = (size_t)plane * PIX;
    const vf4* a4 = (const vf4*)(act + base);
    vf4*       o4 = (vf4*)(out + base);

    // per-wave patch mask in LDS (within-wave RAW only; compiler emits lgkmcnt)
    __shared__ int smask[WAVES][L * KK];
    int* sm = smask[w];
    for (int s = l; s < L * KK; s += 64)
        sm[s] = pmask[(size_t)plane * (L * KK) + s];

    // ---- PASS 1: streaming transform-store (peak-independent) + running max --
    float lmax = -INFINITY;
#pragma unroll
    for (int c = 0; c < CHUNKS; ++c) {
        const int v = l + c * 64;
        if (v < VEC) {                      // only tail chunk is predicated
            vf4 x = a4[v];
            lmax = fmaxf(lmax, rmax4(x));

            const int i    = v / 14;        // row (14 vf4 per row; groups never cross rows)
            const int j0   = (v - i * 14) * 4;
            const int mrow = (i < COVER ? (i / 3) : (L - 1)) * KK;  // clamp: no LDS OOB
            const int c0   = j0 / 3;
            const int c1   = (j0 + 3) / 3;  // group spans <=2 patch cols
            const int ma   = sm[mrow + (c0 < KK ? c0 : KK - 1)];
            const int mb   = sm[mrow + (c1 < KK ? c1 : KK - 1)];
            const bool inrow = (i < COVER);

            vf4 o;
#pragma unroll
            for (int e = 0; e < 4; ++e) {
                const int j  = j0 + e;
                const int mv = ((j / 3) == c0) ? ma : mb;
                const bool cond = inrow && (j < COVER) && (mv != 0);
                o[e] = cond ? x[e] * ALPHA : x[e];
            }
            __builtin_nontemporal_store(o, &o4[v]);   // out never re-read globally
        }
    }

    // ---- wave butterfly max (no LDS, no barrier) ----
    float peak = lmax;
#pragma unroll
    for (int off = 32; off > 0; off >>= 1)
        peak = fmaxf(peak, __shfl_xor(peak, off, 64));

    // ---- PASS 2: fix-up peak pixels. A lane holds a peak pixel iff its
    // local max equals the global peak (elem==peak => elem is the lane max).
    // Typically exactly 1 active lane -> ~13 single-lane L2-hot loads. Exact
    // under ties (exhaustive rescan of candidate lanes). ----
    if (lmax == peak) {
#pragma unroll
        for (int c = 0; c < CHUNKS; ++c) {
            const int v = l + c * 64;
            if (v < VEC) {
                vf4 x = a4[v];              // L2-hot reload, 1 active lane
#pragma unroll
                for (int e = 0; e < 4; ++e) {
                    if (x[e] == peak) {
                        // order against this lane's speculative nt-store
                        asm volatile("s_waitcnt vmcnt(0)" ::: "memory");
                        const size_t p = base + (size_t)(v * 4 + e);
                        out[p] = (rc[p] != 0) ? x[e] * ALPHA : x[e];
                    }
                }
            }
        }
    }
}

extern "C" void kernel_launch(void* const* d_in, const int* in_sizes, int n_in,
                              void* d_out, int out_size, void* d_ws, size_t ws_size,
                              hipStream_t stream) {
    const float* act   = (const float*)d_in[0];
    const int*   rc    = (const int*)d_in[1];
    const int*   pmask = (const int*)d_in[2];
    float*       out   = (float*)d_out;

    const int planes = in_sizes[0] / PIX;               // 32*256 = 8192
    const int blocks = (planes + WAVES - 1) / WAVES;    // 2048
    div_block_kernel<<<blocks, NTHR, 0, stream>>>(act, rc, pmask, out, planes);
}

// Round 6
// 40.374 us; speedup vs baseline: 1.0317x; 1.0302x over previous
//
#include <hip/hip_runtime.h>
#include <math.h>

#define KS     3
#define ALPHA  0.1f
#define M      56
#define N      56
#define L      18
#define KK     18
#define PIX    (M * N)        // 3136
#define VEC    (PIX / 4)      // 784 float4 per plane
#define WAVES  4
#define NTHR   (WAVES * 64)   // 256
#define COVER  (L * KS)       // 54
#define CHUNKS 13             // 12 full rounds of 64 lanes + 16-lane tail

typedef float vf4 __attribute__((ext_vector_type(4)));

__device__ __forceinline__ float rmax4(vf4 x) {
    return fmaxf(fmaxf(x.x, x.y), fmaxf(x.z, x.w));
}

__global__ __launch_bounds__(NTHR) void div_block_kernel(
    const float* __restrict__ act,
    const int*   __restrict__ rc,
    const int*   __restrict__ pmask,
    float*       __restrict__ out,
    int planes) {

    const int tid = threadIdx.x;
    const int w   = tid >> 6;           // wave id in block
    const int l   = tid & 63;           // lane id
    const int plane = blockIdx.x * WAVES + w;
    if (plane >= planes) return;        // no barriers anywhere -> safe

    const size_t base = (size_t)plane * PIX;
    const vf4* a4 = (const vf4*)(act + base);
    vf4*       o4 = (vf4*)(out + base);

    // per-wave patch mask in LDS (within-wave RAW only; no __syncthreads)
    __shared__ int smask[WAVES][L * KK];
    int* sm = smask[w];
    for (int s = l; s < L * KK; s += 64)
        sm[s] = pmask[(size_t)plane * (L * KK) + s];

    // ---- PASS 1: streaming transform-store (peak-independent) ----
    // cand bit c set if chunk c's max >= running max at that time:
    // any chunk containing the final peak is guaranteed flagged (false
    // positives possible, harmless — they just rescan and find no hit).
    float lmax = -INFINITY;
    unsigned cand = 0u;

#pragma unroll
    for (int c = 0; c < CHUNKS; ++c) {
        const int v = l + c * 64;
        if (c < 12 || l < (VEC - 12 * 64)) {   // chunks 0..11 unconditional
            vf4 x = a4[v];
            const float rm = rmax4(x);
            if (rm >= lmax) cand |= (1u << c);
            lmax = fmaxf(lmax, rm);

            const int i    = v / 14;        // row (14 vf4/row; no row crossing)
            const int j0   = (v - i * 14) * 4;
            const int mrow = (i < COVER ? (i / 3) : (L - 1)) * KK;  // clamp
            const int c0   = j0 / 3;
            const int c1   = (j0 + 3) / 3;  // group spans <=2 patch cols
            const int ma   = sm[mrow + (c0 < KK ? c0 : KK - 1)];
            const int mb   = sm[mrow + (c1 < KK ? c1 : KK - 1)];
            const bool inrow = (i < COVER);

            vf4 o;
#pragma unroll
            for (int e = 0; e < 4; ++e) {
                const int j  = j0 + e;
                const int mv = ((j / 3) == c0) ? ma : mb;
                const bool cond = inrow && (j < COVER) && (mv != 0);
                o[e] = cond ? x[e] * ALPHA : x[e];
            }
            o4[v] = o;      // regular store: let L3 cache out across replays
        }
    }

    // ---- wave butterfly max (no LDS, no barrier) ----
    float peak = lmax;
#pragma unroll
    for (int off = 32; off > 0; off >>= 1)
        peak = fmaxf(peak, __shfl_xor(peak, off, 64));

    // ---- PASS 2: fix-up peak pixels. A lane can hold a peak pixel only if
    // its local max equals the plane peak; within it, only flagged chunks can
    // contain it. Typically 1 lane x 1 chunk -> one L2-hot 16B reload. ----
    if (lmax == peak) {
        // order pass-2 stores after this wave's pass-1 stores (same addresses)
        asm volatile("s_waitcnt vmcnt(0)" ::: "memory");
#pragma unroll
        for (int c = 0; c < CHUNKS; ++c) {
            if ((c < 12 || l < (VEC - 12 * 64)) && (cand & (1u << c))) {
                const int v = l + c * 64;
                vf4 x = a4[v];              // L2/L3-hot, ~1 active lane
#pragma unroll
                for (int e = 0; e < 4; ++e) {
                    if (x[e] == peak) {
                        const size_t p = base + (size_t)(v * 4 + e);
                        out[p] = (rc[p] != 0) ? x[e] * ALPHA : x[e];
                    }
                }
            }
        }
    }
}

extern "C" void kernel_launch(void* const* d_in, const int* in_sizes, int n_in,
                              void* d_out, int out_size, void* d_ws, size_t ws_size,
                              hipStream_t stream) {
    const float* act   = (const float*)d_in[0];
    const int*   rc    = (const int*)d_in[1];
    const int*   pmask = (const int*)d_in[2];
    float*       out   = (float*)d_out;

    const int planes = in_sizes[0] / PIX;               // 32*256 = 8192
    const int blocks = (planes + WAVES - 1) / WAVES;    // 2048
    div_block_kernel<<<blocks, NTHR, 0, stream>>>(act, rc, pmask, out, planes);
}